// Round 10
// baseline (396.380 us; speedup 1.0000x reference)
//
#include <hip/hip_runtime.h>
#include <cstdint>
#include <cstddef>

// ---------------------------------------------------------------------------
// Problem constants
// ---------------------------------------------------------------------------
#define BB 2
#define PP 4
#define CC 3
#define HWSZ 65536            // H*W
#define BGH 2764
#define BGW 3856
#define NTAO 27               // 3 lifes x 9 linspace points
#define X4_SIZE (BB*PP*HWSZ)              // 524288
#define TAO_OFF X4_SIZE
#define TAO_SIZE (BB*NTAO*HWSZ)           // 3538944
#define OUT2_OFF (TAO_OFF + TAO_SIZE)     // 4063232
#define NPK 24                            // poisson draws shipped (P(>24)~1e-16)
#define NPB 4                             // draws per batch (ILP)
#define NBLK_A 2048                       // kA blocks

// MEASUREMENT ROUND (retry of r9 with the OOB bg load fixed): in-kernel
// repeats so kA/kC crack the rocprof top-5 (fills sit at ~96 us). z==0 at
// runtime -> results bit-identical to r8; opaque v_mov defeats CSE.
#define REP_A 24
#define REP_C 10

// ---------------------------------------------------------------------------
// rotl via v_alignbit_b32
// ---------------------------------------------------------------------------
__host__ __device__ inline uint32_t rotl32(uint32_t x, int r) {
#ifdef __HIP_DEVICE_COMPILE__
  return __builtin_amdgcn_alignbit(x, x, 32 - r);
#else
  return (x << r) | (x >> (32 - r));
#endif
}

// ---------------------------------------------------------------------------
// Threefry-2x32-20 (jax partitionable mode — verified r2..r8)
// ---------------------------------------------------------------------------
__host__ __device__ inline void tf2x32(uint32_t k0, uint32_t k1,
                                       uint32_t x0, uint32_t x1,
                                       uint32_t& o0, uint32_t& o1) {
  uint32_t ks2 = k0 ^ k1 ^ 0x1BD11BDAu;
  x0 += k0; x1 += k1;
#define TF_RND(r) { x0 += x1; x1 = rotl32(x1, r); x1 ^= x0; }
  TF_RND(13) TF_RND(15) TF_RND(26) TF_RND(6)
  x0 += k1;  x1 += ks2 + 1u;
  TF_RND(17) TF_RND(29) TF_RND(16) TF_RND(24)
  x0 += ks2; x1 += k0 + 2u;
  TF_RND(13) TF_RND(15) TF_RND(26) TF_RND(6)
  x0 += k0;  x1 += k1 + 3u;
  TF_RND(17) TF_RND(29) TF_RND(16) TF_RND(24)
  x0 += k1;  x1 += ks2 + 4u;
  TF_RND(13) TF_RND(15) TF_RND(26) TF_RND(6)
  x0 += ks2; x1 += k0 + 5u;
#undef TF_RND
  o0 = x0; o1 = x1;
}

__host__ __device__ inline uint32_t bits32(uint32_t k0, uint32_t k1, uint32_t e) {
  uint32_t o0, o1;
  tf2x32(k0, k1, 0u, e, o0, o1);
  return o0 ^ o1;
}

// partitionable split: subkey i = RAW pair threefry(key, (0,i))
static void jax_split(uint32_t k0, uint32_t k1, int n, uint32_t (*keys)[2]) {
  for (int i = 0; i < n; ++i)
    tf2x32(k0, k1, 0u, (uint32_t)i, keys[i][0], keys[i][1]);
}

__host__ __device__ inline float u01(uint32_t bits) {
  uint32_t fb = (bits >> 9) | 0x3F800000u;
  return __builtin_bit_cast(float, fb) - 1.0f;
}

// ---------------------------------------------------------------------------
// erfinv (Giles poly == XLA ErfInv32), fast transcendentals
// ---------------------------------------------------------------------------
__device__ inline float erfinv_f(float x) {
  float w = -__logf(fmaf(-x, x, 1.0f));
  float p;
  if (w < 5.0f) {
    w = w - 2.5f;
    p = 2.81022636e-08f;
    p = fmaf(p, w, 3.43273939e-07f);
    p = fmaf(p, w, -3.5233877e-06f);
    p = fmaf(p, w, -4.39150654e-06f);
    p = fmaf(p, w, 0.00021858087f);
    p = fmaf(p, w, -0.00125372503f);
    p = fmaf(p, w, -0.00417768164f);
    p = fmaf(p, w, 0.246640727f);
    p = fmaf(p, w, 1.50140941f);
  } else {
    w = __builtin_amdgcn_sqrtf(w) - 3.0f;
    p = -0.000200214257f;
    p = fmaf(p, w, 0.000100950558f);
    p = fmaf(p, w, 0.00134934322f);
    p = fmaf(p, w, -0.00367342844f);
    p = fmaf(p, w, 0.00573950773f);
    p = fmaf(p, w, -0.0076224613f);
    p = fmaf(p, w, 0.00943887047f);
    p = fmaf(p, w, 1.00167406f);
    p = fmaf(p, w, 2.83297682f);
  }
  return p * x;
}

__device__ inline float normal_e(uint32_t k0, uint32_t k1, uint32_t e) {
  float f = u01(bits32(k0, k1, e));
  const float LO = -0.99999994f;
  float u = fmaxf(LO, fmaf(f, 2.0f, LO));
  return 1.41421356237f * erfinv_f(u);
}

struct PCParams {
  uint32_t kn0, kn1;        // k_norm
  uint32_t kb0, kb1;        // k_bgn
  uint32_t s1[NPK * 2];     // poisson chain subkeys for k_p1
  uint32_t s2[NPK * 2];     // poisson chain subkeys for k_p2
  float bg1[8], bg2[8];
  int idx;
};

// ---------------------------------------------------------------------------
// Batched Knuth step (4-way ILP), exact sequential fp prefix order
// ---------------------------------------------------------------------------
__device__ inline void pk_batch(const uint32_t* __restrict__ sk, int b,
                                uint32_t e, float neg, float& lp, int& k) {
  float l0 = __logf(u01(bits32(sk[(b*NPB+0)*2], sk[(b*NPB+0)*2+1], e)));
  float l1 = __logf(u01(bits32(sk[(b*NPB+1)*2], sk[(b*NPB+1)*2+1], e)));
  float l2 = __logf(u01(bits32(sk[(b*NPB+2)*2], sk[(b*NPB+2)*2+1], e)));
  float l3 = __logf(u01(bits32(sk[(b*NPB+3)*2], sk[(b*NPB+3)*2+1], e)));
  int cnt = (lp > neg) ? 1 : 0;
  float p0 = lp + l0;
  cnt += (p0 > neg) ? 1 : 0;
  float p1 = p0 + l1;
  cnt += (p1 > neg) ? 1 : 0;
  float p2 = p1 + l2;
  cnt += (p2 > neg) ? 1 : 0;
  lp = p2 + l3;
  k += cnt;
}

// ---------------------------------------------------------------------------
// Gaussian ladder (3 exps instead of 9). Accumulates tg9, returns decay.
// ---------------------------------------------------------------------------
__device__ inline float decay_pc(uint32_t kl0, uint32_t kl1, uint32_t ks0,
                                 uint32_t ks1, uint32_t e,
                                 const float (*et)[4], int p, float* tg9) {
  float ul = u01(bits32(kl0, kl1, e));
  float us = u01(bits32(ks0, ks1, e));
  float d0 = -40.0f - (ul - 0.5f) * 12.0f;   // tao0 - Lr (life cancels)
  float sr = fmaf(us - 0.5f, 0.6f, 6.0f);
  float inv = __builtin_amdgcn_rcpf(2.0f * sr * sr);
  float q[9];
  float A  = __expf(-20.0f * inv * d0);
  float Bm = __expf(-100.0f * inv);
  float B2 = Bm * Bm;
  q[0] = __expf(-(d0 * d0) * inv);
  float m = A * Bm;
  float s = q[0];
#pragma unroll
  for (int j = 1; j < 9; ++j) {
    q[j] = q[j - 1] * m;
    m *= B2;
    s += q[j];
  }
  float rs = __builtin_amdgcn_rcpf(s);
  float dec = 0.0f;
#pragma unroll
  for (int j = 0; j < 9; ++j) {
    float wn = q[j] * rs;
    tg9[j] += wn;
    dec = fmaf(et[j][p], wn, dec);
  }
  return dec;
}

// ---------------------------------------------------------------------------
// Kernel A (r8 structure, REP_A measurement reps)
// ---------------------------------------------------------------------------
__global__ __launch_bounds__(256) void kA(
    const float* __restrict__ x, const float* __restrict__ t,
    const float* __restrict__ ratio, const float* __restrict__ life,
    const float* __restrict__ inten, float* __restrict__ out,
    float* __restrict__ bmax,
    uint32_t kl0, uint32_t kl1, uint32_t ks0, uint32_t ks1) {
  __shared__ float et_s[NTAO][4];
  __shared__ float inten_s[3];
  __shared__ float tg_lds[4][9][64];
  __shared__ float bmax_s[4];
  const int tid = threadIdx.x;
  if (tid < NTAO * 4) {
    int j = tid >> 2, p = tid & 3;
    float tao = life[j / 9] + (-40.0f + 10.0f * (float)(j % 9));
    float Tp = fmaxf(t[p] * ratio[p] * 1000.0f, 0.0f);
    et_s[j][p] = expf((-Tp) / tao);
  }
  if (tid < 3) inten_s[tid] = inten[tid];
  __syncthreads();

  const int blk = blockIdx.x;
  const int b = blk >> 10;
  const int hwg = blk & 1023;
  const int p = tid >> 6;
  const int lane = tid & 63;
  const int hw = hwg * 64 + lane;

#pragma clang loop unroll(disable)
  for (int rep = 0; rep < REP_A; ++rep) {
    uint32_t z;
    asm volatile("v_mov_b32 %0, 0" : "=v"(z));   // opaque 0: defeats CSE
    const bool last = (rep == REP_A - 1);

    float acc = 0.0f;

    for (int c = 0; c < 3; ++c) {
      float tg9[9];
#pragma unroll
      for (int j = 0; j < 9; ++j) tg9[j] = 0.0f;

      // e stays in-bounds: z == 0 at runtime, XOR only blocks CSE
      const uint32_t e = ((uint32_t)((((b * 4 + p) * 3 + c) << 16) + hw)) ^ z;
      float dec = decay_pc(kl0, kl1, ks0, ks1, e,
                           (const float(*)[4])&et_s[c * 9], p, tg9);
      acc = fmaf(x[e] * dec, inten_s[c], acc);

#pragma unroll
      for (int j = 0; j < 9; ++j) tg_lds[p][j][lane] = tg9[j];
      __syncthreads();
      for (int jj = p; jj < 9; jj += 4) {
        float s = ((tg_lds[0][jj][lane] + tg_lds[1][jj][lane]) +
                   (tg_lds[2][jj][lane] + tg_lds[3][jj][lane]));
        if (last)
          out[TAO_OFF + ((b * NTAO + c * 9 + jj) << 16) + hw] = s * 0.25f;
        else
          asm volatile("" :: "v"(s));            // keep LDS reads live
      }
      __syncthreads();
    }

    if (last) {
      out[((b * 4 + p) << 16) + hw] = acc;
      float m = acc;
#pragma unroll
      for (int off = 32; off; off >>= 1) m = fmaxf(m, __shfl_xor(m, off));
      if (lane == 0) bmax_s[p] = m;
      __syncthreads();
      if (tid == 0)
        bmax[blk] = fmaxf(fmaxf(bmax_s[0], bmax_s[1]),
                          fmaxf(bmax_s[2], bmax_s[3]));
    } else {
      asm volatile("" :: "v"(acc));              // keep rep live
    }
  }
}

// ---------------------------------------------------------------------------
// Kernel C (r8 structure, REP_C measurement reps).
// FIX vs r9: bg load uses the bounded panel index (p = bp&3), NOT the bgn
// stream index ebg (bp spans 8 panels -> was OOB for bp>=4).
// ---------------------------------------------------------------------------
__global__ __launch_bounds__(256) void kC(
    const float* __restrict__ bgf, const float* __restrict__ t,
    const float* __restrict__ ratio, float* __restrict__ out,
    const float* __restrict__ bmax, PCParams pc) {
  __shared__ float red_s[4];
  __shared__ float mx_s;
  const int tid = threadIdx.x;

  float m = 0.0f;
#pragma unroll
  for (int k = 0; k < 8; ++k) m = fmaxf(m, bmax[tid + 256 * k]);
#pragma unroll
  for (int off = 32; off; off >>= 1) m = fmaxf(m, __shfl_xor(m, off));
  if ((tid & 63) == 0) red_s[tid >> 6] = m;
  __syncthreads();
  if (tid == 0)
    mx_s = fmaxf(fmaxf(red_s[0], red_s[1]), fmaxf(red_s[2], red_s[3]));
  __syncthreads();
  const float mx = mx_s;

  if (blockIdx.x == 0 && tid < 8)
    out[OUT2_OFF + tid] = (tid < 4) ? t[tid] * ratio[tid] : ratio[tid - 4];

  const int e = blockIdx.x * 256 + tid;
  const int bp = e >> 16;
  const int rcc = e & 0xFFFF;
  const int r = rcc >> 8;
  const int cc = rcc & 255;
  const int row = pc.idx + r;
  const int p = bp & 3;
  const float x2 = out[e];
  const float bg = bgf[(p * BGH + row) * BGW + cc];   // bounded: p in [0,4)
  const uint32_t ebg0 = (uint32_t)((bp * BGH + row) * BGW + cc);
  const float xm = x2 * __builtin_amdgcn_rcpf(mx + 0.0001f);
  const float lam1 = fmaxf(xm, 0.0f);
  const bool z1 = !(lam1 > 0.0f);
  const float neg1 = -lam1;

#pragma clang loop unroll(disable)
  for (int rep = 0; rep < REP_C; ++rep) {
    uint32_t z;
    asm volatile("v_mov_b32 %0, 0" : "=v"(z));   // opaque 0: defeats CSE
    const uint32_t ee = ((uint32_t)e) ^ z;
    const uint32_t ebg = ebg0 ^ z;               // register-only use below

    float nb = normal_e(pc.kb0, pc.kb1, ebg);
    float n  = normal_e(pc.kn0, pc.kn1, ee);
    float patch = (bg * pc.bg1[bp] + nb * pc.bg2[bp]) * 0.1f;
    float n_int = fmaf(xm, 5.0f, n);

    float lp1 = 0.0f, lp2 = 0.0f;
    int k1 = 0, k2 = 0;
#pragma clang loop unroll(disable)
    for (int bb = 0; bb < NPK / NPB; ++bb) {
      bool a1 = __any((!z1) && (lp1 > neg1));
      bool a2 = __any(lp2 > -2.0f);
      if (!(a1 || a2)) break;
      if (a1) pk_batch(pc.s1, bb, ee, neg1, lp1, k1);
      if (a2) pk_batch(pc.s2, bb, ee, -2.0f, lp2, k2);
    }
    float pi = z1 ? 0.0f : (float)(k1 - 1);
    float po = (float)(k2 - 1);

    float x3 = ((n_int + pi) + po) + x2;
    float v = x3 + patch;
    v = fminf(fmaxf(v, 0.0f), 255.0f);
    if (rep == REP_C - 1)
      out[e] = v * (1.0f / 255.0f);
    else
      asm volatile("" :: "v"(v));                // keep rep live
  }
}

// ---------------------------------------------------------------------------
// Host
// ---------------------------------------------------------------------------
extern "C" void kernel_launch(void* const* d_in, const int* in_sizes, int n_in,
                              void* d_out, int out_size, void* d_ws, size_t ws_size,
                              hipStream_t stream) {
  const float* x     = (const float*)d_in[0];
  const float* t     = (const float*)d_in[1];
  const float* ratio = (const float*)d_in[2];
  const float* life  = (const float*)d_in[3];
  const float* inten = (const float*)d_in[4];
  const float* bgf   = (const float*)d_in[5];
  float* out = (float*)d_out;
  float* bmax = (float*)d_ws;

  uint32_t sk[9][2];
  jax_split(0u, 42u, 9, sk);

  PCParams pc;
  pc.kn0 = sk[2][0]; pc.kn1 = sk[2][1];
  pc.kb0 = sk[7][0]; pc.kb1 = sk[7][1];

  {
    uint32_t r0 = sk[3][0], r1 = sk[3][1];
    for (int i = 0; i < NPK; ++i) {
      uint32_t two[2][2];
      jax_split(r0, r1, 2, two);
      pc.s1[2*i] = two[1][0]; pc.s1[2*i+1] = two[1][1];
      r0 = two[0][0]; r1 = two[0][1];
    }
    r0 = sk[4][0]; r1 = sk[4][1];
    for (int i = 0; i < NPK; ++i) {
      uint32_t two[2][2];
      jax_split(r0, r1, 2, two);
      pc.s2[2*i] = two[1][0]; pc.s2[2*i+1] = two[1][1];
      r0 = two[0][0]; r1 = two[0][1];
    }
  }

  for (uint32_t i = 0; i < 8; ++i) {
    pc.bg1[i] = u01(bits32(sk[5][0], sk[5][1], i)) * 0.5f + 0.5f;
    pc.bg2[i] = u01(bits32(sk[6][0], sk[6][1], i)) * 0.5f + 0.5f;
  }

  {
    uint32_t hi = bits32(sk[8][0], sk[8][1], 0u);
    uint32_t lo = bits32(sk[8][0], sk[8][1], 1u);
    const uint32_t span = 9u;
    uint32_t mult = (65536u % span);
    mult = (mult * mult) % span;
    uint32_t off = ((hi % span) * mult + (lo % span)) % span;
    pc.idx = (int)off;
  }

  kA<<<NBLK_A, 256, 0, stream>>>(x, t, ratio, life, inten, out, bmax,
                                 sk[0][0], sk[0][1], sk[1][0], sk[1][1]);
  kC<<<X4_SIZE / 256, 256, 0, stream>>>(bgf, t, ratio, out, bmax, pc);
}

// Round 11
// 36.434 us; speedup vs baseline: 10.8795x; 10.8795x over previous
//
#include <hip/hip_runtime.h>
#include <cstdint>
#include <cstddef>

// ---------------------------------------------------------------------------
// Problem constants
// ---------------------------------------------------------------------------
#define BB 2
#define PP 4
#define CC 3
#define HWSZ 65536            // H*W
#define BGH 2764
#define BGW 3856
#define NTAO 27               // 3 lifes x 9 linspace points
#define X4_SIZE (BB*PP*HWSZ)              // 524288
#define TAO_OFF X4_SIZE
#define TAO_SIZE (BB*NTAO*HWSZ)           // 3538944
#define OUT2_OFF (TAO_OFF + TAO_SIZE)     // 4063232
#define NPK 24                            // poisson draws shipped (P(>24)~1e-16)
#define NBLK_A 2048                       // kA blocks

// ---------------------------------------------------------------------------
// rotl via v_alignbit_b32
// ---------------------------------------------------------------------------
__host__ __device__ inline uint32_t rotl32(uint32_t x, int r) {
#ifdef __HIP_DEVICE_COMPILE__
  return __builtin_amdgcn_alignbit(x, x, 32 - r);
#else
  return (x << r) | (x >> (32 - r));
#endif
}

// ---------------------------------------------------------------------------
// Threefry-2x32-20 (jax partitionable mode — verified r2..r10)
// ---------------------------------------------------------------------------
__host__ __device__ inline void tf2x32(uint32_t k0, uint32_t k1,
                                       uint32_t x0, uint32_t x1,
                                       uint32_t& o0, uint32_t& o1) {
  uint32_t ks2 = k0 ^ k1 ^ 0x1BD11BDAu;
  x0 += k0; x1 += k1;
#define TF_RND(r) { x0 += x1; x1 = rotl32(x1, r); x1 ^= x0; }
  TF_RND(13) TF_RND(15) TF_RND(26) TF_RND(6)
  x0 += k1;  x1 += ks2 + 1u;
  TF_RND(17) TF_RND(29) TF_RND(16) TF_RND(24)
  x0 += ks2; x1 += k0 + 2u;
  TF_RND(13) TF_RND(15) TF_RND(26) TF_RND(6)
  x0 += k0;  x1 += k1 + 3u;
  TF_RND(17) TF_RND(29) TF_RND(16) TF_RND(24)
  x0 += k1;  x1 += ks2 + 4u;
  TF_RND(13) TF_RND(15) TF_RND(26) TF_RND(6)
  x0 += ks2; x1 += k0 + 5u;
#undef TF_RND
  o0 = x0; o1 = x1;
}

__host__ __device__ inline uint32_t bits32(uint32_t k0, uint32_t k1, uint32_t e) {
  uint32_t o0, o1;
  tf2x32(k0, k1, 0u, e, o0, o1);
  return o0 ^ o1;
}

// partitionable split: subkey i = RAW pair threefry(key, (0,i))
static void jax_split(uint32_t k0, uint32_t k1, int n, uint32_t (*keys)[2]) {
  for (int i = 0; i < n; ++i)
    tf2x32(k0, k1, 0u, (uint32_t)i, keys[i][0], keys[i][1]);
}

__host__ __device__ inline float u01(uint32_t bits) {
  uint32_t fb = (bits >> 9) | 0x3F800000u;
  return __builtin_bit_cast(float, fb) - 1.0f;
}

// ---------------------------------------------------------------------------
// erfinv (Giles poly == XLA ErfInv32), fast transcendentals
// ---------------------------------------------------------------------------
__device__ inline float erfinv_f(float x) {
  float w = -__logf(fmaf(-x, x, 1.0f));
  float p;
  if (w < 5.0f) {
    w = w - 2.5f;
    p = 2.81022636e-08f;
    p = fmaf(p, w, 3.43273939e-07f);
    p = fmaf(p, w, -3.5233877e-06f);
    p = fmaf(p, w, -4.39150654e-06f);
    p = fmaf(p, w, 0.00021858087f);
    p = fmaf(p, w, -0.00125372503f);
    p = fmaf(p, w, -0.00417768164f);
    p = fmaf(p, w, 0.246640727f);
    p = fmaf(p, w, 1.50140941f);
  } else {
    w = __builtin_amdgcn_sqrtf(w) - 3.0f;
    p = -0.000200214257f;
    p = fmaf(p, w, 0.000100950558f);
    p = fmaf(p, w, 0.00134934322f);
    p = fmaf(p, w, -0.00367342844f);
    p = fmaf(p, w, 0.00573950773f);
    p = fmaf(p, w, -0.0076224613f);
    p = fmaf(p, w, 0.00943887047f);
    p = fmaf(p, w, 1.00167406f);
    p = fmaf(p, w, 2.83297682f);
  }
  return p * x;
}

__device__ inline float normal_e(uint32_t k0, uint32_t k1, uint32_t e) {
  float f = u01(bits32(k0, k1, e));
  const float LO = -0.99999994f;
  float u = fmaxf(LO, fmaf(f, 2.0f, LO));
  return 1.41421356237f * erfinv_f(u);
}

struct PCParams {
  uint32_t kn0, kn1;        // k_norm
  uint32_t kb0, kb1;        // k_bgn
  uint32_t s1[NPK * 2];     // poisson chain subkeys for k_p1
  uint32_t s2[NPK * 2];     // poisson chain subkeys for k_p2
  float bg1[8], bg2[8];
  int idx;
};

// ---------------------------------------------------------------------------
// Product-form Knuth count, granularity 2 (r10 measurement-driven):
// count = #{j>=1 : prod_{i<j} u_i > T}, T = e^{-lam}. P monotone decreasing
// so the set is a prefix — identical counts to the reference's log-sum form
// up to ~1-ulp borderline flips (each worth 1/255 = 0.0039 << 0.02 threshold).
// No v_log in the loop; ~10 instead of 12 threefry at wave-max ~8 draws.
// ---------------------------------------------------------------------------
__device__ inline int pk_count2(const uint32_t* __restrict__ sk,
                                uint32_t e, float T) {
  float P = 1.0f;
  int cnt = 0;
#pragma clang loop unroll(disable)
  for (int i = 0; i < NPK; i += 2) {
    if (!__any(P > T)) break;
    float u0 = u01(bits32(sk[2*i],     sk[2*i+1],     e));
    float u1 = u01(bits32(sk[2*i+2],   sk[2*i+3],     e));
    float P0 = P * u0;
    float P1 = P0 * u1;
    cnt += (P0 > T) ? 1 : 0;
    cnt += (P1 > T) ? 1 : 0;
    P = P1;
  }
  return cnt;
}

// ---------------------------------------------------------------------------
// Gaussian ladder (3 exps instead of 9). Accumulates tg9, returns decay.
// ---------------------------------------------------------------------------
__device__ inline float decay_pc(uint32_t kl0, uint32_t kl1, uint32_t ks0,
                                 uint32_t ks1, uint32_t e,
                                 const float (*et)[4], int p, float* tg9) {
  float ul = u01(bits32(kl0, kl1, e));
  float us = u01(bits32(ks0, ks1, e));
  float d0 = -40.0f - (ul - 0.5f) * 12.0f;   // tao0 - Lr (life cancels)
  float sr = fmaf(us - 0.5f, 0.6f, 6.0f);
  float inv = __builtin_amdgcn_rcpf(2.0f * sr * sr);
  float q[9];
  float A  = __expf(-20.0f * inv * d0);
  float Bm = __expf(-100.0f * inv);
  float B2 = Bm * Bm;
  q[0] = __expf(-(d0 * d0) * inv);
  float m = A * Bm;
  float s = q[0];
#pragma unroll
  for (int j = 1; j < 9; ++j) {
    q[j] = q[j - 1] * m;
    m *= B2;
    s += q[j];
  }
  float rs = __builtin_amdgcn_rcpf(s);
  float dec = 0.0f;
#pragma unroll
  for (int j = 0; j < 9; ++j) {
    float wn = q[j] * rs;
    tg9[j] += wn;
    dec = fmaf(et[j][p], wn, dec);
  }
  return dec;
}

// ---------------------------------------------------------------------------
// Kernel A (r8-proven, issue-bound at 9.8us): 2048 blocks x 256.
// Thread = (b, p=wave, hw). tao_gt p-mean via LDS; block max -> bmax[blk].
// ---------------------------------------------------------------------------
__global__ __launch_bounds__(256) void kA(
    const float* __restrict__ x, const float* __restrict__ t,
    const float* __restrict__ ratio, const float* __restrict__ life,
    const float* __restrict__ inten, float* __restrict__ out,
    float* __restrict__ bmax,
    uint32_t kl0, uint32_t kl1, uint32_t ks0, uint32_t ks1) {
  __shared__ float et_s[NTAO][4];
  __shared__ float inten_s[3];
  __shared__ float tg_lds[4][9][64];
  __shared__ float bmax_s[4];
  const int tid = threadIdx.x;
  if (tid < NTAO * 4) {
    int j = tid >> 2, p = tid & 3;
    float tao = life[j / 9] + (-40.0f + 10.0f * (float)(j % 9));
    float Tp = fmaxf(t[p] * ratio[p] * 1000.0f, 0.0f);
    et_s[j][p] = expf((-Tp) / tao);
  }
  if (tid < 3) inten_s[tid] = inten[tid];
  __syncthreads();

  const int blk = blockIdx.x;
  const int b = blk >> 10;
  const int hwg = blk & 1023;
  const int p = tid >> 6;
  const int lane = tid & 63;
  const int hw = hwg * 64 + lane;

  float acc = 0.0f;

  for (int c = 0; c < 3; ++c) {
    float tg9[9];
#pragma unroll
    for (int j = 0; j < 9; ++j) tg9[j] = 0.0f;

    const uint32_t e = (uint32_t)((((b * 4 + p) * 3 + c) << 16) + hw);
    float dec = decay_pc(kl0, kl1, ks0, ks1, e,
                         (const float(*)[4])&et_s[c * 9], p, tg9);
    acc = fmaf(x[e] * dec, inten_s[c], acc);

#pragma unroll
    for (int j = 0; j < 9; ++j) tg_lds[p][j][lane] = tg9[j];
    __syncthreads();
    for (int jj = p; jj < 9; jj += 4) {
      float s = ((tg_lds[0][jj][lane] + tg_lds[1][jj][lane]) +
                 (tg_lds[2][jj][lane] + tg_lds[3][jj][lane]));
      out[TAO_OFF + ((b * NTAO + c * 9 + jj) << 16) + hw] = s * 0.25f;
    }
    __syncthreads();
  }

  out[((b * 4 + p) << 16) + hw] = acc;   // x2 staged in the x4 slot

  float m = acc;
#pragma unroll
  for (int off = 32; off; off >>= 1) m = fmaxf(m, __shfl_xor(m, off));
  if (lane == 0) bmax_s[p] = m;
  __syncthreads();
  if (tid == 0)
    bmax[blk] = fmaxf(fmaxf(bmax_s[0], bmax_s[1]),
                      fmaxf(bmax_s[2], bmax_s[3]));
}

// ---------------------------------------------------------------------------
// Kernel C: noise + background patch -> x4. One thread per element.
// Poisson now product-form, granularity-2, no logs (r10 counters: poisson
// was ~75% of the 15.5us body; this trims draws 16->~12 and kills 16 v_log).
// ---------------------------------------------------------------------------
__global__ __launch_bounds__(256) void kC(
    const float* __restrict__ bgf, const float* __restrict__ t,
    const float* __restrict__ ratio, float* __restrict__ out,
    const float* __restrict__ bmax, PCParams pc) {
  __shared__ float red_s[4];
  __shared__ float mx_s;
  const int tid = threadIdx.x;

  // global max from bmax[2048]
  float m = 0.0f;
#pragma unroll
  for (int k = 0; k < 8; ++k) m = fmaxf(m, bmax[tid + 256 * k]);
#pragma unroll
  for (int off = 32; off; off >>= 1) m = fmaxf(m, __shfl_xor(m, off));
  if ((tid & 63) == 0) red_s[tid >> 6] = m;
  __syncthreads();
  if (tid == 0)
    mx_s = fmaxf(fmaxf(red_s[0], red_s[1]), fmaxf(red_s[2], red_s[3]));
  __syncthreads();
  const float mx = mx_s;

  if (blockIdx.x == 0 && tid < 8)
    out[OUT2_OFF + tid] = (tid < 4) ? t[tid] * ratio[tid] : ratio[tid - 4];

  const int e = blockIdx.x * 256 + tid;   // [0, 524288)
  const int bp = e >> 16;
  const int rcc = e & 0xFFFF;
  const int r = rcc >> 8;
  const int cc = rcc & 255;

  const int row = pc.idx + r;
  const int p = bp & 3;
  const float bg = bgf[(p * BGH + row) * BGW + cc];
  const float x2 = out[e];

  const uint32_t ebg = (uint32_t)((bp * BGH + row) * BGW + cc);
  float nb = normal_e(pc.kb0, pc.kb1, ebg);
  float n  = normal_e(pc.kn0, pc.kn1, (uint32_t)e);
  float patch = (bg * pc.bg1[bp] + nb * pc.bg2[bp]) * 0.1f;

  const float xm = x2 * __builtin_amdgcn_rcpf(mx + 0.0001f);
  float n_int = fmaf(xm, 5.0f, n);

  // Poisson counts, product form
  const float lam1 = fmaxf(xm, 0.0f);
  const bool z1 = !(lam1 > 0.0f);
  float pi = 0.0f;
  if (!z1) {
    float T1 = __expf(-lam1);
    pi = (float)pk_count2(pc.s1, (uint32_t)e, T1);
  }
  const float T2 = 0.13533528f;        // e^-2
  float po = (float)pk_count2(pc.s2, (uint32_t)e, T2);

  float x3 = ((n_int + pi) + po) + x2;
  float v = x3 + patch;
  v = fminf(fmaxf(v, 0.0f), 255.0f);
  out[e] = v * (1.0f / 255.0f);
}

// ---------------------------------------------------------------------------
// Host
// ---------------------------------------------------------------------------
extern "C" void kernel_launch(void* const* d_in, const int* in_sizes, int n_in,
                              void* d_out, int out_size, void* d_ws, size_t ws_size,
                              hipStream_t stream) {
  const float* x     = (const float*)d_in[0];
  const float* t     = (const float*)d_in[1];
  const float* ratio = (const float*)d_in[2];
  const float* life  = (const float*)d_in[3];
  const float* inten = (const float*)d_in[4];
  const float* bgf   = (const float*)d_in[5];
  float* out = (float*)d_out;
  float* bmax = (float*)d_ws;

  uint32_t sk[9][2];
  jax_split(0u, 42u, 9, sk);

  PCParams pc;
  pc.kn0 = sk[2][0]; pc.kn1 = sk[2][1];
  pc.kb0 = sk[7][0]; pc.kb1 = sk[7][1];

  {
    uint32_t r0 = sk[3][0], r1 = sk[3][1];
    for (int i = 0; i < NPK; ++i) {
      uint32_t two[2][2];
      jax_split(r0, r1, 2, two);
      pc.s1[2*i] = two[1][0]; pc.s1[2*i+1] = two[1][1];
      r0 = two[0][0]; r1 = two[0][1];
    }
    r0 = sk[4][0]; r1 = sk[4][1];
    for (int i = 0; i < NPK; ++i) {
      uint32_t two[2][2];
      jax_split(r0, r1, 2, two);
      pc.s2[2*i] = two[1][0]; pc.s2[2*i+1] = two[1][1];
      r0 = two[0][0]; r1 = two[0][1];
    }
  }

  for (uint32_t i = 0; i < 8; ++i) {
    pc.bg1[i] = u01(bits32(sk[5][0], sk[5][1], i)) * 0.5f + 0.5f;
    pc.bg2[i] = u01(bits32(sk[6][0], sk[6][1], i)) * 0.5f + 0.5f;
  }

  {
    uint32_t hi = bits32(sk[8][0], sk[8][1], 0u);
    uint32_t lo = bits32(sk[8][0], sk[8][1], 1u);
    const uint32_t span = 9u;
    uint32_t mult = (65536u % span);
    mult = (mult * mult) % span;
    uint32_t off = ((hi % span) * mult + (lo % span)) % span;
    pc.idx = (int)off;
  }

  kA<<<NBLK_A, 256, 0, stream>>>(x, t, ratio, life, inten, out, bmax,
                                 sk[0][0], sk[0][1], sk[1][0], sk[1][1]);
  kC<<<X4_SIZE / 256, 256, 0, stream>>>(bgf, t, ratio, out, bmax, pc);
}